// Round 1
// baseline (93.540 us; speedup 1.0000x reference)
//
#include <hip/hip_runtime.h>

#define K_DIM 131072
#define NROW 256
#define BK 64
#define TPB 512
#define TEMP 14.285714285714286f

typedef float f32x4 __attribute__((ext_vector_type(4)));
typedef short s16x8 __attribute__((ext_vector_type(8)));

// fp32 -> bf16 round-to-nearest-even, packed pair into one u32
__device__ __forceinline__ unsigned int pack2bf(float a, float b) {
    unsigned int ua = __float_as_uint(a);
    ua = (ua + 0x7FFFu + ((ua >> 16) & 1u)) >> 16;
    unsigned int ub = __float_as_uint(b);
    ub = (ub + 0x7FFFu + ((ub >> 16) & 1u)) & 0xFFFF0000u;
    return ua | ub;
}

// Stage 1: split-K GEMM. Each block: full 256x256 partial C over K-chunk KC.
// 8 waves, each owns a 128x64 output tile. LDS tiles bf16, XOR-swizzled.
__global__ __launch_bounds__(TPB, 2) void gemm_splitk(
    const float* __restrict__ A, const float* __restrict__ Bm,
    float* __restrict__ partials, int KC)
{
    __shared__ __align__(16) unsigned short As[2][NROW * BK];  // 32 KB each
    __shared__ __align__(16) unsigned short Bs[2][NROW * BK];

    const int t    = threadIdx.x;
    const int lane = t & 63;
    const int wid  = t >> 6;
    const int wr   = (wid >> 2) * 128;   // wave row base in C
    const int wc   = (wid & 3) * 64;     // wave col base in C

    const int srow = t >> 4;             // staging row within 32-row group
    const int scol = (t & 15) * 4;       // staging f32 col (0..60)

    const long k0base = (long)blockIdx.x * (long)KC;
    const int  NS     = KC / BK;

    f32x4 regA[8], regB[8];
    f32x4 acc[8][4];
#pragma unroll
    for (int m = 0; m < 8; ++m)
#pragma unroll
        for (int n = 0; n < 4; ++n)
            acc[m][n] = f32x4{0.f, 0.f, 0.f, 0.f};

    const float* aP = A  + (long)srow * K_DIM + k0base + scol;
    const float* bP = Bm + (long)srow * K_DIM + k0base + scol;

    // prologue: load K-tile 0 into registers
#pragma unroll
    for (int r = 0; r < 8; ++r) {
        regA[r] = *(const f32x4*)(aP + (long)r * 32 * K_DIM);
        regB[r] = *(const f32x4*)(bP + (long)r * 32 * K_DIM);
    }

    for (int s = 0; s < NS; ++s) {
        unsigned short* as = As[s & 1];
        unsigned short* bs = Bs[s & 1];

        // convert + write current tile to LDS (swizzled: byte ^= (row&7)<<4)
#pragma unroll
        for (int r = 0; r < 8; ++r) {
            int row = r * 32 + srow;
            int off = (row * 128 + scol * 2) ^ ((row & 7) << 4);
            uint2 va = make_uint2(pack2bf(regA[r].x, regA[r].y),
                                  pack2bf(regA[r].z, regA[r].w));
            uint2 vb = make_uint2(pack2bf(regB[r].x, regB[r].y),
                                  pack2bf(regB[r].z, regB[r].w));
            *(uint2*)((char*)as + off) = va;
            *(uint2*)((char*)bs + off) = vb;
        }

        // prefetch next K-tile into registers (stays in flight across barrier)
        if (s + 1 < NS) {
            const long koff = (long)(s + 1) * BK;
#pragma unroll
            for (int r = 0; r < 8; ++r) {
                regA[r] = *(const f32x4*)(aP + (long)r * 32 * K_DIM + koff);
                regB[r] = *(const f32x4*)(bP + (long)r * 32 * K_DIM + koff);
            }
        }

        // raw barrier: drain LDS only, do NOT drain vmcnt (keep prefetch in flight)
        asm volatile("s_waitcnt lgkmcnt(0)\n\ts_barrier" ::: "memory");

        // MFMA phase over buf[s&1]
#pragma unroll
        for (int ks = 0; ks < 2; ++ks) {
            s16x8 bf[4];
#pragma unroll
            for (int n = 0; n < 4; ++n) {
                int row = wc + n * 16 + (lane & 15);
                int off = (row * 128 + ks * 64 + ((lane >> 4) * 16)) ^ ((row & 7) << 4);
                bf[n] = *(const s16x8*)((const char*)bs + off);
            }
#pragma unroll
            for (int m = 0; m < 8; ++m) {
                int row = wr + m * 16 + (lane & 15);
                int off = (row * 128 + ks * 64 + ((lane >> 4) * 16)) ^ ((row & 7) << 4);
                s16x8 af = *(const s16x8*)((const char*)as + off);
#pragma unroll
                for (int n = 0; n < 4; ++n)
                    acc[m][n] = __builtin_amdgcn_mfma_f32_16x16x32_bf16(af, bf[n], acc[m][n], 0, 0, 0);
            }
        }
    }

    // epilogue: write fp32 partial tile. C/D map: col=lane&15, row=(lane>>4)*4+j
    float* outp = partials + (size_t)blockIdx.x * (NROW * NROW);
    const int lr = (lane >> 4) * 4;
    const int lc = lane & 15;
#pragma unroll
    for (int m = 0; m < 8; ++m)
#pragma unroll
        for (int n = 0; n < 4; ++n) {
#pragma unroll
            for (int j = 0; j < 4; ++j)
                outp[(size_t)(wr + m * 16 + lr + j) * NROW + (wc + n * 16 + lc)] = acc[m][n][j];
        }
}

// Stage 2: reduce partials over split; per-row masked exp, rowsum, pos, rowloss; store E.
__global__ __launch_bounds__(NROW) void reduce_loss_rows(
    const float* __restrict__ partials, const int* __restrict__ idx,
    float* __restrict__ E, float* __restrict__ rowloss, float* __restrict__ posbuf,
    int split)
{
    const int b = blockIdx.x;   // row
    const int t = threadIdx.x;  // col
    const float* p = partials + b * NROW + t;
    float sum = 0.f;
#pragma unroll 8
    for (int s = 0; s < split; ++s)
        sum += p[(size_t)s * (NROW * NROW)];

    const float logit = sum * TEMP;
    const bool  mask  = (idx[b] != idx[t]) || (b == t);
    const float e     = mask ? expf(logit) : 0.0f;
    E[b * NROW + t] = e;

    __shared__ float red[NROW];
    __shared__ float posv;
    if (t == b) posv = logit;
    red[t] = e;
    __syncthreads();
#pragma unroll
    for (int s = NROW / 2; s > 0; s >>= 1) {
        if (t < s) red[t] += red[t + s];
        __syncthreads();
    }
    if (t == 0) {
        posbuf[b]  = posv;
        rowloss[b] = logf(red[0]) - posv;
    }
}

// Stage 3: column sums of E, column losses, final mean.
__global__ __launch_bounds__(NROW) void finalize_loss(
    const float* __restrict__ E, const float* __restrict__ rowloss,
    const float* __restrict__ posbuf, float* __restrict__ out)
{
    const int t = threadIdx.x;
    float csum = 0.f;
#pragma unroll 8
    for (int i = 0; i < NROW; ++i)
        csum += E[i * NROW + t];
    const float closs = logf(csum) - posbuf[t];
    const float rl    = rowloss[t];

    __shared__ float redc[NROW];
    __shared__ float redr[NROW];
    redc[t] = closs;
    redr[t] = rl;
    __syncthreads();
#pragma unroll
    for (int s = NROW / 2; s > 0; s >>= 1) {
        if (t < s) { redc[t] += redc[t + s]; redr[t] += redr[t + s]; }
        __syncthreads();
    }
    if (t == 0)
        out[0] = 0.5f * (redc[0] + redr[0]) * (1.0f / (float)NROW);
}

extern "C" void kernel_launch(void* const* d_in, const int* in_sizes, int n_in,
                              void* d_out, int out_size, void* d_ws, size_t ws_size,
                              hipStream_t stream)
{
    (void)in_sizes; (void)n_in; (void)out_size;
    const float* A   = (const float*)d_in[0];
    const float* Bm  = (const float*)d_in[1];
    const int*   idx = (const int*)d_in[2];
    float*       out = (float*)d_out;

    // adaptive split-K based on workspace size (partials: split * 256KB)
    int split = 256;
    const size_t extra = (size_t)(NROW * NROW + 2 * NROW) * sizeof(float);
    while (split > 1 &&
           (size_t)split * NROW * NROW * sizeof(float) + extra > ws_size)
        split >>= 1;
    const int KC = K_DIM / split;

    float* partials = (float*)d_ws;
    float* E        = partials + (size_t)split * NROW * NROW;
    float* rowloss  = E + NROW * NROW;
    float* posbuf   = rowloss + NROW;

    gemm_splitk<<<split, TPB, 0, stream>>>(A, Bm, partials, KC);
    reduce_loss_rows<<<NROW, NROW, 0, stream>>>(partials, idx, E, rowloss, posbuf, split);
    finalize_loss<<<1, NROW, 0, stream>>>(E, rowloss, posbuf, out);
}